// Round 1
// baseline (120.002 us; speedup 1.0000x reference)
//
#include <hip/hip_runtime.h>
#include <hip/hip_bf16.h>
#include <math.h>

#define A_TOTAL 250000
#define BCNT 8
#define NANN 16

// ws layout:
//  [0, 6144)        : ann table, (b,n) stride 12 floats:
//                     0:x1 1:y1 2:x2 3:y2 4:area 5:cx 6:cy 7:th 8:len 9:cls 10,11:pad
//  [6144, 7168)     : keys, B*N u64  (iou_bits<<32 | (0xFFFFFFFF - anchor))
//  [7168, 7264)     : acc, B*3 floats (cls_sum, reg_sum, npos)

__device__ __forceinline__ float focal_term(float pc, bool is_one) {
    // pc already clipped
    if (is_one) return 0.25f * (1.f - pc) * (1.f - pc) * (-logf(pc));
    return 0.75f * pc * pc * (-logf(1.f - pc));
}

__global__ __launch_bounds__(256) void detloss_init(
    const float* __restrict__ ann, float* __restrict__ table,
    unsigned long long* __restrict__ keys, float* __restrict__ acc)
{
    int tid = threadIdx.x;
    if (tid < BCNT * NANN) {
        const float* a = ann + tid * 5;
        float cx = a[0], cy = a[1], th = a[2], ln = a[3], cl = a[4];
        float dx = fabsf(0.5f * ln * cosf(th));
        float dy = fabsf(0.5f * ln * sinf(th));
        float x1 = cx - dx, y1 = cy - dy, x2 = cx + dx, y2 = cy + dy;
        float* t = table + tid * 12;
        t[0] = x1; t[1] = y1; t[2] = x2; t[3] = y2;
        t[4] = (x2 - x1) * (y2 - y1);
        t[5] = cx; t[6] = cy; t[7] = th; t[8] = ln; t[9] = cl;
        t[10] = 0.f; t[11] = 0.f;
        keys[tid] = 0ULL;
    }
    if (tid < BCNT * 3) acc[tid] = 0.f;
}

__global__ __launch_bounds__(256) void detloss_main(
    const float* __restrict__ cls, const float* __restrict__ reg,
    const float* __restrict__ anchors, const float* __restrict__ table,
    unsigned long long* __restrict__ keys, float* __restrict__ acc)
{
    int b = blockIdx.y;
    __shared__ float sAnn[NANN * 12];
    __shared__ unsigned long long sKey[4][NANN];
    __shared__ float sPart[4][3];
    int tid = threadIdx.x;
    if (tid < NANN * 12) sAnn[tid] = table[b * NANN * 12 + tid];
    __syncthreads();

    unsigned long long key[NANN];
#pragma unroll
    for (int n = 0; n < NANN; n++) key[n] = 0ULL;
    float clsS = 0.f, regS = 0.f, nposS = 0.f;

    const float4* clsB = (const float4*)(cls + (size_t)b * A_TOTAL * 4);
    const float4* regB = (const float4*)(reg + (size_t)b * A_TOTAL * 4);
    const float4* anc4 = (const float4*)anchors;

    for (int a = blockIdx.x * blockDim.x + tid; a < A_TOTAL; a += gridDim.x * blockDim.x) {
        float4 ap = anc4[a];
        float aw = ap.z - ap.x, ah = ap.w - ap.y;
        float aarea = aw * ah;
        float best = -1.f; int barg = 0;
#pragma unroll
        for (int n = 0; n < NANN; n++) {
            const float* an = &sAnn[n * 12];
            float iw = fminf(ap.z, an[2]) - fmaxf(ap.x, an[0]);
            float ih = fminf(ap.w, an[3]) - fmaxf(ap.y, an[1]);
            iw = fmaxf(iw, 0.f); ih = fmaxf(ih, 0.f);
            float inter = iw * ih;
            float ua = fmaxf(aarea + an[4] - inter, 1e-8f);
            float iou = inter / ua;
            bool valid = (an[9] != -1.0f);
            float iv = valid ? iou : -1.f;
            if (iv > best) { best = iv; barg = n; }
            if (valid) {
                unsigned long long k =
                    ((unsigned long long)__float_as_uint(iou) << 32) |
                    (unsigned long long)(0xFFFFFFFFu - (unsigned)a);
                if (k > key[n]) key[n] = k;
            }
        }
        // per-anchor loss (skip ignore band [0.4, 0.5))
        if (best < 0.4f || best >= 0.5f) {
            float4 p4 = clsB[a];
            float p[4] = {p4.x, p4.y, p4.z, p4.w};
            bool pos = (best >= 0.5f);
            int ac = pos ? (int)sAnn[barg * 12 + 9] : -1;
            float fl = 0.f;
#pragma unroll
            for (int c = 0; c < 4; c++) {
                float pc = fminf(fmaxf(p[c], 1e-4f), 1.f - 1e-4f);
                fl += focal_term(pc, c == ac);
            }
            clsS += fl;
            if (pos) {
                nposS += 1.f;
                float4 r = regB[a];
                float cxa = (ap.x + ap.z) * 0.5f, cya = (ap.y + ap.w) * 0.5f;
                float L = sqrtf(aw * aw + ah * ah);
                float th = (ap.x == ap.z) ? copysignf(1.5707963267948966f, ah)
                                          : atanf(ah / aw);
                float pr0 = r.x * aw + cxa;
                float pr1 = r.y * ah + cya;
                float pr2 = r.z + th;
                float pr3 = expf(r.w) * L;
                float g0 = sAnn[barg * 12 + 5], g1 = sAnn[barg * 12 + 6];
                float g2 = sAnn[barg * 12 + 7], g3 = sAnn[barg * 12 + 8];
                float s = 0.f;
                float d, ad;
                d = pr0 - g0; ad = fabsf(d); s += (ad < 1.f) ? 0.5f * d * d : ad - 0.5f;
                d = pr1 - g1; ad = fabsf(d); s += (ad < 1.f) ? 0.5f * d * d : ad - 0.5f;
                d = pr2 - g2; ad = fabsf(d); s += (ad < 1.f) ? 0.5f * d * d : ad - 0.5f;
                d = pr3 - g3; ad = fabsf(d); s += (ad < 1.f) ? 0.5f * d * d : ad - 0.5f;
                regS += s * 0.25f;
            }
        }
    }

    int lane = tid & 63, wv = tid >> 6;
#pragma unroll
    for (int n = 0; n < NANN; n++) {
        unsigned long long k = key[n];
        for (int off = 32; off > 0; off >>= 1) {
            unsigned long long o = __shfl_xor(k, off, 64);
            if (o > k) k = o;
        }
        if (lane == 0) sKey[wv][n] = k;
    }
    for (int off = 32; off > 0; off >>= 1) {
        clsS  += __shfl_xor(clsS, off, 64);
        regS  += __shfl_xor(regS, off, 64);
        nposS += __shfl_xor(nposS, off, 64);
    }
    if (lane == 0) { sPart[wv][0] = clsS; sPart[wv][1] = regS; sPart[wv][2] = nposS; }
    __syncthreads();
    if (tid < NANN) {
        unsigned long long k = sKey[0][tid];
#pragma unroll
        for (int w = 1; w < 4; w++) if (sKey[w][tid] > k) k = sKey[w][tid];
        atomicMax(&keys[b * NANN + tid], k);
    }
    if (tid == 0) {
        float c0 = 0, c1 = 0, c2 = 0;
        for (int w = 0; w < 4; w++) { c0 += sPart[w][0]; c1 += sPart[w][1]; c2 += sPart[w][2]; }
        atomicAdd(&acc[b * 3 + 0], c0);
        atomicAdd(&acc[b * 3 + 1], c1);
        atomicAdd(&acc[b * 3 + 2], c2);
    }
}

__global__ __launch_bounds__(256) void detloss_fin(
    const float* __restrict__ cls, const float* __restrict__ reg,
    const float* __restrict__ anchors, const float* __restrict__ table,
    const unsigned long long* __restrict__ keys, const float* __restrict__ acc,
    float* __restrict__ out)
{
    __shared__ int sForce[BCNT][NANN];
    __shared__ float sAcc[BCNT][3];
    int tid = threadIdx.x;
    if (tid < BCNT * 3) sAcc[tid / 3][tid % 3] = acc[tid];
    if (tid < BCNT * NANN) {
        int b = tid / NANN, n = tid % NANN;
        unsigned long long k = keys[tid];
        float amax = __uint_as_float((unsigned)(k >> 32));
        float bcls = table[(b * NANN + n) * 12 + 9];
        bool force = (bcls != -1.f) && (amax < 0.5f) && (k != 0ULL);
        int anchor = (int)(0xFFFFFFFFu - (unsigned)(k & 0xFFFFFFFFu));
        sForce[b][n] = (force && anchor >= 0 && anchor < A_TOTAL) ? anchor : -1;
    }
    __syncthreads();
    if (tid < BCNT) {
        int b = tid;
        const float* tb = table + b * NANN * 12;
        const float4* clsB = (const float4*)(cls + (size_t)b * A_TOTAL * 4);
        const float4* regB = (const float4*)(reg + (size_t)b * A_TOTAL * 4);
        const float4* anc4 = (const float4*)anchors;
        float dC = 0.f, dR = 0.f, dN = 0.f;
        for (int n = 0; n < NANN; n++) {
            int idx = sForce[b][n];
            if (idx < 0) continue;
            bool first = true;
            for (int m = 0; m < n; m++) if (sForce[b][m] == idx) first = false;
            if (!first) continue;

            float4 ap = anc4[idx];
            float aw = ap.z - ap.x, ah = ap.w - ap.y;
            float aarea = aw * ah;
            // --- old state of this anchor (must match main kernel bit-for-bit) ---
            float best = -1.f; int barg = 0;
            for (int m = 0; m < NANN; m++) {
                const float* an = &tb[m * 12];
                float iw = fminf(ap.z, an[2]) - fmaxf(ap.x, an[0]);
                float ih = fminf(ap.w, an[3]) - fmaxf(ap.y, an[1]);
                iw = fmaxf(iw, 0.f); ih = fmaxf(ih, 0.f);
                float inter = iw * ih;
                float ua = fmaxf(aarea + an[4] - inter, 1e-8f);
                float iou = inter / ua;
                bool valid2 = (an[9] != -1.f);
                float iv = valid2 ? iou : -1.f;
                if (iv > best) { best = iv; barg = m; }
            }
            float4 p4 = clsB[idx];
            float p[4] = {p4.x, p4.y, p4.z, p4.w};
            float cxa = (ap.x + ap.z) * 0.5f, cya = (ap.y + ap.w) * 0.5f;
            float L = sqrtf(aw * aw + ah * ah);
            float th = (ap.x == ap.z) ? copysignf(1.5707963267948966f, ah)
                                      : atanf(ah / aw);
            float oldc = 0.f, oldr = 0.f, oldn = 0.f;
            if (best < 0.4f || best >= 0.5f) {
                bool pos = (best >= 0.5f);
                int ac = pos ? (int)tb[barg * 12 + 9] : -1;
                for (int c = 0; c < 4; c++) {
                    float pc = fminf(fmaxf(p[c], 1e-4f), 1.f - 1e-4f);
                    oldc += focal_term(pc, c == ac);
                }
                if (pos) {
                    oldn = 1.f;
                    float4 r = regB[idx];
                    float pr0 = r.x * aw + cxa;
                    float pr1 = r.y * ah + cya;
                    float pr2 = r.z + th;
                    float pr3 = expf(r.w) * L;
                    float s = 0.f, d, ad;
                    d = pr0 - tb[barg * 12 + 5]; ad = fabsf(d); s += (ad < 1.f) ? 0.5f * d * d : ad - 0.5f;
                    d = pr1 - tb[barg * 12 + 6]; ad = fabsf(d); s += (ad < 1.f) ? 0.5f * d * d : ad - 0.5f;
                    d = pr2 - tb[barg * 12 + 7]; ad = fabsf(d); s += (ad < 1.f) ? 0.5f * d * d : ad - 0.5f;
                    d = pr3 - tb[barg * 12 + 8]; ad = fabsf(d); s += (ad < 1.f) ? 0.5f * d * d : ad - 0.5f;
                    oldr = s * 0.25f;
                }
            }
            // --- new state: row = union of onehots of all forced anns hitting idx ---
            unsigned cmask = 0; int lastm = n;
            for (int m = 0; m < NANN; m++)
                if (sForce[b][m] == idx) { cmask |= 1u << (int)tb[m * 12 + 9]; lastm = m; }
            float newc = 0.f;
            for (int c = 0; c < 4; c++) {
                float pc = fminf(fmaxf(p[c], 1e-4f), 1.f - 1e-4f);
                newc += focal_term(pc, (cmask >> c) & 1);
            }
            float4 r = regB[idx];
            float pr0 = r.x * aw + cxa;
            float pr1 = r.y * ah + cya;
            float pr2 = r.z + th;
            float pr3 = expf(r.w) * L;
            float s = 0.f, d, ad;
            d = pr0 - tb[lastm * 12 + 5]; ad = fabsf(d); s += (ad < 1.f) ? 0.5f * d * d : ad - 0.5f;
            d = pr1 - tb[lastm * 12 + 6]; ad = fabsf(d); s += (ad < 1.f) ? 0.5f * d * d : ad - 0.5f;
            d = pr2 - tb[lastm * 12 + 7]; ad = fabsf(d); s += (ad < 1.f) ? 0.5f * d * d : ad - 0.5f;
            d = pr3 - tb[lastm * 12 + 8]; ad = fabsf(d); s += (ad < 1.f) ? 0.5f * d * d : ad - 0.5f;
            float newr = s * 0.25f;

            dC += newc - oldc;
            dR += newr - oldr;
            dN += 1.f - oldn;
        }
        sAcc[b][0] += dC; sAcc[b][1] += dR; sAcc[b][2] += dN;
    }
    __syncthreads();
    if (tid == 0) {
        float cm = 0.f, rm = 0.f;
        for (int b = 0; b < BCNT; b++) {
            float np = fmaxf(sAcc[b][2], 1.f);
            cm += sAcc[b][0] / np;
            rm += sAcc[b][1] / np;
        }
        out[0] = cm * 0.125f;
        out[1] = rm * 0.125f;
    }
}

extern "C" void kernel_launch(void* const* d_in, const int* in_sizes, int n_in,
                              void* d_out, int out_size, void* d_ws, size_t ws_size,
                              hipStream_t stream) {
    const float* classifications = (const float*)d_in[0];
    const float* regressions     = (const float*)d_in[1];
    const float* anchors_pos     = (const float*)d_in[2];
    const float* annotations     = (const float*)d_in[3];
    float* out = (float*)d_out;

    char* ws = (char*)d_ws;
    float* table = (float*)(ws + 0);
    unsigned long long* keys = (unsigned long long*)(ws + 6144);
    float* acc = (float*)(ws + 7168);

    detloss_init<<<1, 256, 0, stream>>>(annotations, table, keys, acc);
    detloss_main<<<dim3(128, BCNT), 256, 0, stream>>>(
        classifications, regressions, anchors_pos, table, keys, acc);
    detloss_fin<<<1, 256, 0, stream>>>(
        classifications, regressions, anchors_pos, table, keys, acc, out);
}